// Round 1
// baseline (644.371 us; speedup 1.0000x reference)
//
#include <hip/hip_runtime.h>

#define Q 2048
#define NTRAIN 65536
#define D 768
#define KNN 7

#define BM 128
#define BN 128
#define BK 64
#define KT (D / BK)          // 12
#define NCT (NTRAIN / BN)    // 512 column tiles
#define TSEL 8               // candidates kept per (row, tile)

typedef __attribute__((ext_vector_type(8))) short short8;
typedef __attribute__((ext_vector_type(4))) float f32x4;

// ---- ws layout (bytes) ----
// Xb  : Q*D*2          =   3,145,728
// Tb  : N*D*2          = 100,663,296
// tsq : N*4            =     262,144
// cand: Q*NCT*TSEL*4   =  33,554,432   (total ~131.3 MB)
static constexpr size_t XB_OFF   = 0;
static constexpr size_t TB_OFF   = XB_OFF + (size_t)Q * D * 2;
static constexpr size_t TSQ_OFF  = TB_OFF + (size_t)NTRAIN * D * 2;
static constexpr size_t CAND_OFF = TSQ_OFF + (size_t)NTRAIN * 4;

__device__ __forceinline__ unsigned short f2b(float f) {
    unsigned u = __float_as_uint(f);
    unsigned r = (u + 0x7FFFu + ((u >> 16) & 1u)) >> 16;   // RNE bf16
    return (unsigned short)r;
}

__device__ __forceinline__ unsigned pack32(float f) {
    // monotone u32: a<b  =>  pack32(a) < pack32(b)
    unsigned u = __float_as_uint(f);
    return (u & 0x80000000u) ? ~u : (u | 0x80000000u);
}

__device__ __forceinline__ void gload16(const void* g, void* l) {
    __builtin_amdgcn_global_load_lds(
        (const __attribute__((address_space(1))) unsigned*)g,
        (__attribute__((address_space(3))) unsigned*)l, 16, 0, 0);
}

// ---------------- Kernel 1: fp32 -> bf16 + row sq-norms ----------------
// one row per block, 192 threads, one float4 each
__global__ void prep_kernel(const float* __restrict__ src,
                            unsigned short* __restrict__ dst,
                            float* __restrict__ sq, int nrows) {
    __shared__ float red[3];
    const int row = blockIdx.x;
    if (row >= nrows) return;
    const int t = threadIdx.x;
    float4 v = reinterpret_cast<const float4*>(src)[(size_t)row * (D / 4) + t];
    ushort4 o;
    o.x = f2b(v.x); o.y = f2b(v.y); o.z = f2b(v.z); o.w = f2b(v.w);
    reinterpret_cast<ushort4*>(dst)[(size_t)row * (D / 4) + t] = o;
    if (sq) {
        float s = v.x * v.x + v.y * v.y + v.z * v.z + v.w * v.w;
#pragma unroll
        for (int off = 32; off; off >>= 1) s += __shfl_down(s, off);
        if ((t & 63) == 0) red[t >> 6] = s;
        __syncthreads();
        if (t == 0) sq[row] = red[0] + red[1] + red[2];
    }
}

// ---------------- Kernel 2: bf16 MFMA GEMM + per-tile top-8 ----------------
__global__ void __launch_bounds__(256) knn_gemm_kernel(
    const unsigned short* __restrict__ Xb, const unsigned short* __restrict__ Tb,
    const float* __restrict__ tsq, unsigned* __restrict__ cand) {
    // smem union: [0,16384) A-tile bf16[128][64], [16384,32768) B-tile,
    // epilogue: [0,32768) keys u16[128][128]; [32768,40960) merge u32[256][8]
    __shared__ __align__(16) char smem[40960];
    const int tid  = threadIdx.x;
    const int wave = tid >> 6, lane = tid & 63;
    const int rowTile = blockIdx.x, colTile = blockIdx.y;
    const int wr = wave >> 1, wc = wave & 1;

    const f32x4 zero = {0.f, 0.f, 0.f, 0.f};
    f32x4 acc[4][4];
#pragma unroll
    for (int m = 0; m < 4; m++)
#pragma unroll
        for (int n = 0; n < 4; n++) acc[m][n] = zero;

    // staging: chunk c covers LDS rows [c*32, c*32+32); 4 lanes... layout:
    // lds linear byte = c*4096 + wave*1024 + lane*16  -> row = c*32+wave*8+(lane>>3)
    // within-row granule (16B) = lane&7; source pre-swizzled: g_src = (lane&7) ^ (row&7)
    const int s_row = wave * 8 + (lane >> 3);              // row within 32-row chunk
    const int s_col = (((lane & 7) ^ (s_row & 7)) * 8);    // element offset (swizzled src)
    const unsigned short* gA = Xb + (size_t)(rowTile * BM + s_row) * D + s_col;
    const unsigned short* gB = Tb + (size_t)(colTile * BN + s_row) * D + s_col;
    char* Asm = smem;
    char* Bsm = smem + 16384;

    for (int kt = 0; kt < KT; ++kt) {
        const int k0 = kt * BK;
        __syncthreads();   // previous tile's reads done before overwrite
#pragma unroll
        for (int c = 0; c < 4; ++c) {
            gload16(gA + (size_t)c * 32 * D + k0, Asm + c * 4096 + wave * 1024);
            gload16(gB + (size_t)c * 32 * D + k0, Bsm + c * 4096 + wave * 1024);
        }
        __syncthreads();   // compiler drains vmcnt before barrier
#pragma unroll
        for (int kk = 0; kk < 2; ++kk) {
            short8 a[4], b[4];
            const int g = kk * 4 + (lane >> 4);   // granule (16B) index in row
#pragma unroll
            for (int m = 0; m < 4; m++) {
                const int row = wr * 64 + m * 16 + (lane & 15);
                a[m] = *(const short8*)(Asm + row * 128 + ((g ^ (row & 7)) * 16));
            }
#pragma unroll
            for (int n = 0; n < 4; n++) {
                const int row = wc * 64 + n * 16 + (lane & 15);
                b[n] = *(const short8*)(Bsm + row * 128 + ((g ^ (row & 7)) * 16));
            }
#pragma unroll
            for (int m = 0; m < 4; m++)
#pragma unroll
                for (int n = 0; n < 4; n++)
                    acc[m][n] = __builtin_amdgcn_mfma_f32_16x16x32_bf16(a[m], b[n], acc[m][n], 0, 0, 0);
        }
    }
    __syncthreads();   // all MFMA-feeding ds_reads done before key overwrite

    // keys: key = tsq[col] - 2*cross  (x_sq is per-row constant: irrelevant to ranking)
    float tsqv[4];
#pragma unroll
    for (int n = 0; n < 4; n++)
        tsqv[n] = tsq[colTile * BN + wc * 64 + n * 16 + (lane & 15)];
    unsigned short* keys = (unsigned short*)smem;   // [128][128]
    const int crow = wr * 64 + (lane >> 4) * 4;
    const int ccol = wc * 64 + (lane & 15);
#pragma unroll
    for (int m = 0; m < 4; m++)
#pragma unroll
        for (int n = 0; n < 4; n++)
#pragma unroll
            for (int r = 0; r < 4; r++) {
                float key = fmaf(-2.f, acc[m][n][r], tsqv[n]);
                keys[(crow + m * 16 + r) * 128 + (ccol + n * 16)] =
                    (unsigned short)(pack32(key) >> 16);
            }
    __syncthreads();

    // per-row top-8: 2 threads/row, each scans 64 cols (rotated to spread banks)
    unsigned arr[8];
#pragma unroll
    for (int j = 0; j < 8; j++) arr[j] = 0xFFFFFFFFu;
    const int srow = tid >> 1;
    const int c0 = (tid & 1) * 64;
    const unsigned gcb = colTile * BN + c0;
    const unsigned short* krow = keys + srow * 128 + c0;
    for (int cc = 0; cc < 64; cc++) {
        const int c = (cc + srow) & 63;
        unsigned v = ((unsigned)krow[c] << 16) | (gcb + c);
        if (v < arr[7]) {
            arr[7] = v;
            for (int j = 7; j > 0; j--) {
                if (arr[j] < arr[j - 1]) { unsigned t = arr[j]; arr[j] = arr[j - 1]; arr[j - 1] = t; }
                else break;
            }
        }
    }
    unsigned* mrg = (unsigned*)(smem + 32768);
#pragma unroll
    for (int j = 0; j < 8; j++) mrg[tid * 8 + j] = arr[j];
    __syncthreads();
    if ((tid & 1) == 0) {
        const unsigned* other = mrg + (tid + 1) * 8;
        unsigned outv[8];
        int i = 0, j = 0;
#pragma unroll
        for (int k = 0; k < 8; k++) {          // i+j==k<=7 so no OOB
            unsigned av = arr[i], bv = other[j];
            if (av <= bv) { outv[k] = av; ++i; } else { outv[k] = bv; ++j; }
        }
        unsigned* dst = cand + ((size_t)(rowTile * BM + srow) * NCT + colTile) * TSEL;
#pragma unroll
        for (int k = 0; k < 8; k++) dst[k] = outv[k];
    }
}

// ---------------- Kernel 3: approx top-16 -> exact fp32 re-rank -> mean ----------------
__global__ void __launch_bounds__(256) knn_reduce_kernel(
    const float* __restrict__ X, const float* __restrict__ Xt,
    const float* __restrict__ tsq, const float* __restrict__ y,
    const unsigned* __restrict__ cand, float* __restrict__ out) {
    __shared__ unsigned cl[4096];
    __shared__ float xrow[D];
    __shared__ float red[4];
    __shared__ unsigned wmin[4];
    __shared__ float xsqs;
    __shared__ unsigned sel[16];
    __shared__ float exd[16];
    __shared__ unsigned exi[16];
    const int q = blockIdx.x;
    const int tid = threadIdx.x;
    const int lane = tid & 63, wave = tid >> 6;

    const unsigned* cq = cand + (size_t)q * (NCT * TSEL);
#pragma unroll
    for (int j = 0; j < 16; j++) cl[j * 256 + tid] = cq[j * 256 + tid];
    if (tid < D / 4)
        ((float4*)xrow)[tid] = ((const float4*)(X + (size_t)q * D))[tid];
    __syncthreads();

    // exact x_sq
    float xs = 0.f;
#pragma unroll
    for (int j = 0; j < 3; j++) { float v = xrow[tid + j * 256]; xs = fmaf(v, v, xs); }
#pragma unroll
    for (int off = 32; off; off >>= 1) xs += __shfl_down(xs, off);
    if (lane == 0) red[wave] = xs;
    __syncthreads();
    if (tid == 0) xsqs = red[0] + red[1] + red[2] + red[3];

    // 16 rounds of block-argmin over 4096 packed candidates (thread owns cl[tid + 256*j])
    for (int r = 0; r < 16; r++) {
        unsigned mn = 0xFFFFFFFFu;
#pragma unroll
        for (int j = 0; j < 16; j++) { unsigned v = cl[tid + 256 * j]; mn = v < mn ? v : mn; }
#pragma unroll
        for (int off = 32; off; off >>= 1) {
            unsigned o = (unsigned)__shfl_xor((int)mn, off);
            mn = o < mn ? o : mn;
        }
        if (lane == 0) wmin[wave] = mn;
        __syncthreads();
        unsigned m01 = wmin[0] < wmin[1] ? wmin[0] : wmin[1];
        unsigned m23 = wmin[2] < wmin[3] ? wmin[2] : wmin[3];
        unsigned m = m01 < m23 ? m01 : m23;
        if (tid == 0) sel[r] = m;
#pragma unroll
        for (int j = 0; j < 16; j++)
            if (cl[tid + 256 * j] == m) cl[tid + 256 * j] = 0xFFFFFFFFu;
        __syncthreads();
    }

    // exact fp32 distance for the 16 candidates (one wave per candidate, 4 rounds)
    for (int cc = wave; cc < 16; cc += 4) {
        const unsigned id = sel[cc] & 0xFFFFu;
        const float* trow = Xt + (size_t)id * D;
        float s = 0.f;
#pragma unroll
        for (int j = 0; j < 12; j++) s = fmaf(xrow[lane + j * 64], trow[lane + j * 64], s);
#pragma unroll
        for (int off = 32; off; off >>= 1) s += __shfl_xor(s, off);
        if (lane == 0) {
            float d2 = xsqs + tsq[id] - 2.f * s;
            exd[cc] = sqrtf(fmaxf(d2, 0.f));
            exi[cc] = id;
        }
    }
    __syncthreads();

    if (tid == 0) {
        bool taken[16];
#pragma unroll
        for (int j = 0; j < 16; j++) taken[j] = false;
        float accy = 0.f;
        for (int k = 0; k < KNN; k++) {   // ascending dist, tie -> lower index (== top_k order)
            int best = -1;
            for (int j = 0; j < 16; j++) {
                if (taken[j]) continue;
                if (best < 0 || exd[j] < exd[best] ||
                    (exd[j] == exd[best] && exi[j] < exi[best])) best = j;
            }
            taken[best] = true;
            accy += y[exi[best]];
        }
        out[q] = accy / 7.0f;
    }
}

extern "C" void kernel_launch(void* const* d_in, const int* in_sizes, int n_in,
                              void* d_out, int out_size, void* d_ws, size_t ws_size,
                              hipStream_t stream) {
    const float* X  = (const float*)d_in[0];
    const float* Xt = (const float*)d_in[1];
    const float* y  = (const float*)d_in[2];
    float* out = (float*)d_out;
    char* ws = (char*)d_ws;
    unsigned short* Xb = (unsigned short*)(ws + XB_OFF);
    unsigned short* Tb = (unsigned short*)(ws + TB_OFF);
    float* tsq = (float*)(ws + TSQ_OFF);
    unsigned* cand = (unsigned*)(ws + CAND_OFF);

    prep_kernel<<<dim3(Q), dim3(192), 0, stream>>>(X, Xb, (float*)nullptr, Q);
    prep_kernel<<<dim3(NTRAIN), dim3(192), 0, stream>>>(Xt, Tb, tsq, NTRAIN);
    knn_gemm_kernel<<<dim3(Q / BM, NCT), dim3(256), 0, stream>>>(Xb, Tb, tsq, cand);
    knn_reduce_kernel<<<dim3(Q), dim3(256), 0, stream>>>(X, Xt, tsq, y, cand, out);
}

// Round 2
// 423.773 us; speedup vs baseline: 1.5206x; 1.5206x over previous
//
#include <hip/hip_runtime.h>

#define Q 2048
#define NTRAIN 65536
#define D 768
#define KNN 7

#define BM 128
#define BN 128
#define BK 64
#define KT (D / BK)          // 12
#define NCT (NTRAIN / BN)    // 512 column tiles
#define TSEL 8               // candidates kept per (row, tile)

typedef __attribute__((ext_vector_type(8))) short short8;
typedef __attribute__((ext_vector_type(4))) float f32x4;

// ---- ws layout (bytes) ----
static constexpr size_t XB_OFF   = 0;
static constexpr size_t TB_OFF   = XB_OFF + (size_t)Q * D * 2;
static constexpr size_t TSQ_OFF  = TB_OFF + (size_t)NTRAIN * D * 2;
static constexpr size_t CAND_OFF = TSQ_OFF + (size_t)NTRAIN * 4;

__device__ __forceinline__ unsigned short f2b(float f) {
    unsigned u = __float_as_uint(f);
    unsigned r = (u + 0x7FFFu + ((u >> 16) & 1u)) >> 16;   // RNE bf16
    return (unsigned short)r;
}

__device__ __forceinline__ unsigned pack32(float f) {
    unsigned u = __float_as_uint(f);
    return (u & 0x80000000u) ? ~u : (u | 0x80000000u);
}

__device__ __forceinline__ void gload16(const void* g, void* l) {
    __builtin_amdgcn_global_load_lds(
        (const __attribute__((address_space(1))) unsigned*)g,
        (__attribute__((address_space(3))) unsigned*)l, 16, 0, 0);
}

// ---------------- Kernel 1: fp32 -> bf16 + row sq-norms ----------------
__global__ void prep_kernel(const float* __restrict__ src,
                            unsigned short* __restrict__ dst,
                            float* __restrict__ sq, int nrows) {
    __shared__ float red[3];
    const int row = blockIdx.x;
    if (row >= nrows) return;
    const int t = threadIdx.x;
    float4 v = reinterpret_cast<const float4*>(src)[(size_t)row * (D / 4) + t];
    ushort4 o;
    o.x = f2b(v.x); o.y = f2b(v.y); o.z = f2b(v.z); o.w = f2b(v.w);
    reinterpret_cast<ushort4*>(dst)[(size_t)row * (D / 4) + t] = o;
    if (sq) {
        float s = v.x * v.x + v.y * v.y + v.z * v.z + v.w * v.w;
#pragma unroll
        for (int off = 32; off; off >>= 1) s += __shfl_down(s, off);
        if ((t & 63) == 0) red[t >> 6] = s;
        __syncthreads();
        if (t == 0) sq[row] = red[0] + red[1] + red[2];
    }
}

// ---------------- Kernel 2: bf16 MFMA GEMM + per-tile top-8 ----------------
__global__ void __launch_bounds__(256) knn_gemm_kernel(
    const unsigned short* __restrict__ Xb, const unsigned short* __restrict__ Tb,
    const float* __restrict__ tsq, unsigned* __restrict__ cand) {
    // smem union: [0,16384) A-tile bf16[128][64], [16384,32768) B-tile
    // epilogue: [0,32768) keys u16[128][128] (col-swizzled)
    __shared__ __align__(16) char smem[32768];
    const int tid  = threadIdx.x;
    const int wave = tid >> 6, lane = tid & 63;
    const int rowTile = blockIdx.x, colTile = blockIdx.y;
    const int wr = wave >> 1, wc = wave & 1;

    const f32x4 zero = {0.f, 0.f, 0.f, 0.f};
    f32x4 acc[4][4];
#pragma unroll
    for (int m = 0; m < 4; m++)
#pragma unroll
        for (int n = 0; n < 4; n++) acc[m][n] = zero;

    // staging layout identical to R1 (verified): lds byte = c*4096 + wave*1024 + lane*16
    const int s_row = wave * 8 + (lane >> 3);
    const int s_col = (((lane & 7) ^ (s_row & 7)) * 8);
    const unsigned short* gA = Xb + (size_t)(rowTile * BM + s_row) * D + s_col;
    const unsigned short* gB = Tb + (size_t)(colTile * BN + s_row) * D + s_col;
    char* Asm = smem;
    char* Bsm = smem + 16384;

    for (int kt = 0; kt < KT; ++kt) {
        const int k0 = kt * BK;
        __syncthreads();
#pragma unroll
        for (int c = 0; c < 4; ++c) {
            gload16(gA + (size_t)c * 32 * D + k0, Asm + c * 4096 + wave * 1024);
            gload16(gB + (size_t)c * 32 * D + k0, Bsm + c * 4096 + wave * 1024);
        }
        __syncthreads();
#pragma unroll
        for (int kk = 0; kk < 2; ++kk) {
            short8 a[4], b[4];
            const int g = kk * 4 + (lane >> 4);
#pragma unroll
            for (int m = 0; m < 4; m++) {
                const int row = wr * 64 + m * 16 + (lane & 15);
                a[m] = *(const short8*)(Asm + row * 128 + ((g ^ (row & 7)) * 16));
            }
#pragma unroll
            for (int n = 0; n < 4; n++) {
                const int row = wc * 64 + n * 16 + (lane & 15);
                b[n] = *(const short8*)(Bsm + row * 128 + ((g ^ (row & 7)) * 16));
            }
#pragma unroll
            for (int m = 0; m < 4; m++)
#pragma unroll
                for (int n = 0; n < 4; n++)
                    acc[m][n] = __builtin_amdgcn_mfma_f32_16x16x32_bf16(a[m], b[n], acc[m][n], 0, 0, 0);
        }
    }
    __syncthreads();   // all MFMA-feeding ds_reads done before key overwrite

    // keys: key = tsq[col] - 2*cross; store u16 at col ^ ((row&12)<<2)
    // (flips col bits 4/5 per 4-row group -> the 4 row-groups of one b16 store
    //  instr land on disjoint bank quartets -> conflict-free)
    float tsqv[4];
#pragma unroll
    for (int n = 0; n < 4; n++)
        tsqv[n] = tsq[colTile * BN + wc * 64 + n * 16 + (lane & 15)];
    unsigned short* keys = (unsigned short*)smem;   // [128][128] swizzled
    const int crow = wr * 64 + ((lane >> 4) << 2);
    const int ccol = wc * 64 + (lane & 15);
#pragma unroll
    for (int m = 0; m < 4; m++)
#pragma unroll
        for (int n = 0; n < 4; n++)
#pragma unroll
            for (int r = 0; r < 4; r++) {
                const int row = crow + m * 16 + r;
                const int col = ccol + n * 16;
                float key = fmaf(-2.f, acc[m][n][r], tsqv[n]);
                keys[row * 128 + (col ^ ((row & 12) << 2))] =
                    (unsigned short)(pack32(key) >> 16);
            }
    __syncthreads();

    // branchless per-half top-4: 2 threads/row, each scans 32 u32 words (64 cols)
    // srow-rotated word order -> each bank hit by exactly 2 lanes (free)
    const int srow = tid >> 1, h = tid & 1;
    const unsigned sx = (unsigned)((srow & 12) << 2);
    const unsigned* keys32 = (const unsigned*)smem;
    const unsigned base = (unsigned)(srow * 64 + h * 32);
    const unsigned gcb = (unsigned)(colTile * BN + h * 64);
    unsigned m1 = ~0u, m2 = ~0u, m3 = ~0u, m4 = ~0u;
#pragma unroll 8
    for (int ii = 0; ii < 32; ++ii) {
        const unsigned w = (unsigned)((ii + srow) & 31);
        const unsigned pair = keys32[base + w];
        const unsigned gc = gcb + ((w * 2) ^ sx);
        const unsigned v0 = (pair << 16) | gc;
        const unsigned v1 = (pair & 0xFFFF0000u) | (gc + 1);
        unsigned t0, t1, t2;
        t0 = max(m1, v0); m1 = min(m1, v0);
        t1 = max(m2, t0); m2 = min(m2, t0);
        t2 = max(m3, t1); m3 = min(m3, t1);
        m4 = min(m4, t2);
        t0 = max(m1, v1); m1 = min(m1, v1);
        t1 = max(m2, t0); m2 = min(m2, t0);
        t2 = max(m3, t1); m3 = min(m3, t1);
        m4 = min(m4, t2);
    }
    uint4 outv = {m1, m2, m3, m4};
    *reinterpret_cast<uint4*>(
        cand + ((size_t)(rowTile * BM + srow) * NCT + colTile) * TSEL + h * 4) = outv;
}

// ---------------- Kernel 3: approx top-16 -> exact fp32 re-rank -> mean ----------------
__global__ void __launch_bounds__(256) knn_reduce_kernel(
    const float* __restrict__ X, const float* __restrict__ Xt,
    const float* __restrict__ tsq, const float* __restrict__ y,
    const unsigned* __restrict__ cand, float* __restrict__ out) {
    __shared__ unsigned cl[4096];
    __shared__ float xrow[D];
    __shared__ float red[4];
    __shared__ unsigned wmin[4];
    __shared__ float xsqs;
    __shared__ unsigned sel[16];
    __shared__ float exd[16];
    __shared__ unsigned exi[16];
    const int q = blockIdx.x;
    const int tid = threadIdx.x;
    const int lane = tid & 63, wave = tid >> 6;

    const unsigned* cq = cand + (size_t)q * (NCT * TSEL);
#pragma unroll
    for (int j = 0; j < 16; j++) cl[j * 256 + tid] = cq[j * 256 + tid];
    if (tid < D / 4)
        ((float4*)xrow)[tid] = ((const float4*)(X + (size_t)q * D))[tid];
    __syncthreads();

    float xs = 0.f;
#pragma unroll
    for (int j = 0; j < 3; j++) { float v = xrow[tid + j * 256]; xs = fmaf(v, v, xs); }
#pragma unroll
    for (int off = 32; off; off >>= 1) xs += __shfl_down(xs, off);
    if (lane == 0) red[wave] = xs;
    __syncthreads();
    if (tid == 0) xsqs = red[0] + red[1] + red[2] + red[3];

    for (int r = 0; r < 16; r++) {
        unsigned mn = 0xFFFFFFFFu;
#pragma unroll
        for (int j = 0; j < 16; j++) { unsigned v = cl[tid + 256 * j]; mn = v < mn ? v : mn; }
#pragma unroll
        for (int off = 32; off; off >>= 1) {
            unsigned o = (unsigned)__shfl_xor((int)mn, off);
            mn = o < mn ? o : mn;
        }
        if (lane == 0) wmin[wave] = mn;
        __syncthreads();
        unsigned m01 = wmin[0] < wmin[1] ? wmin[0] : wmin[1];
        unsigned m23 = wmin[2] < wmin[3] ? wmin[2] : wmin[3];
        unsigned m = m01 < m23 ? m01 : m23;
        if (tid == 0) sel[r] = m;
#pragma unroll
        for (int j = 0; j < 16; j++)
            if (cl[tid + 256 * j] == m) cl[tid + 256 * j] = 0xFFFFFFFFu;
        __syncthreads();
    }

    for (int cc = wave; cc < 16; cc += 4) {
        const unsigned id = sel[cc] & 0xFFFFu;
        const float* trow = Xt + (size_t)id * D;
        float s = 0.f;
#pragma unroll
        for (int j = 0; j < 12; j++) s = fmaf(xrow[lane + j * 64], trow[lane + j * 64], s);
#pragma unroll
        for (int off = 32; off; off >>= 1) s += __shfl_xor(s, off);
        if (lane == 0) {
            float d2 = xsqs + tsq[id] - 2.f * s;
            exd[cc] = sqrtf(fmaxf(d2, 0.f));
            exi[cc] = id;
        }
    }
    __syncthreads();

    if (tid == 0) {
        bool taken[16];
#pragma unroll
        for (int j = 0; j < 16; j++) taken[j] = false;
        float accy = 0.f;
        for (int k = 0; k < KNN; k++) {
            int best = -1;
            for (int j = 0; j < 16; j++) {
                if (taken[j]) continue;
                if (best < 0 || exd[j] < exd[best] ||
                    (exd[j] == exd[best] && exi[j] < exi[best])) best = j;
            }
            taken[best] = true;
            accy += y[exi[best]];
        }
        out[q] = accy / 7.0f;
    }
}

extern "C" void kernel_launch(void* const* d_in, const int* in_sizes, int n_in,
                              void* d_out, int out_size, void* d_ws, size_t ws_size,
                              hipStream_t stream) {
    const float* X  = (const float*)d_in[0];
    const float* Xt = (const float*)d_in[1];
    const float* y  = (const float*)d_in[2];
    float* out = (float*)d_out;
    char* ws = (char*)d_ws;
    unsigned short* Xb = (unsigned short*)(ws + XB_OFF);
    unsigned short* Tb = (unsigned short*)(ws + TB_OFF);
    float* tsq = (float*)(ws + TSQ_OFF);
    unsigned* cand = (unsigned*)(ws + CAND_OFF);

    prep_kernel<<<dim3(Q), dim3(192), 0, stream>>>(X, Xb, (float*)nullptr, Q);
    prep_kernel<<<dim3(NTRAIN), dim3(192), 0, stream>>>(Xt, Tb, tsq, NTRAIN);
    knn_gemm_kernel<<<dim3(Q / BM, NCT), dim3(256), 0, stream>>>(Xb, Tb, tsq, cand);
    knn_reduce_kernel<<<dim3(Q), dim3(256), 0, stream>>>(X, Xt, tsq, y, cand, out);
}

// Round 3
// 330.447 us; speedup vs baseline: 1.9500x; 1.2824x over previous
//
#include <hip/hip_runtime.h>

#define Q 2048
#define NTRAIN 65536
#define D 768
#define KNN 7

#define BM 128
#define BN 128
#define BK 64
#define KT (D / BK)          // 12
#define NCT (NTRAIN / BN)    // 512 column tiles
#define TSEL 8               // candidates kept per (row, tile)

typedef __attribute__((ext_vector_type(8))) short short8;
typedef __attribute__((ext_vector_type(4))) float f32x4;

// ---- ws layout (bytes) ----
static constexpr size_t XB_OFF   = 0;
static constexpr size_t TB_OFF   = XB_OFF + (size_t)Q * D * 2;
static constexpr size_t TSQ_OFF  = TB_OFF + (size_t)NTRAIN * D * 2;
static constexpr size_t CAND_OFF = TSQ_OFF + (size_t)NTRAIN * 4;

__device__ __forceinline__ unsigned short f2b(float f) {
    unsigned u = __float_as_uint(f);
    unsigned r = (u + 0x7FFFu + ((u >> 16) & 1u)) >> 16;   // RNE bf16
    return (unsigned short)r;
}

__device__ __forceinline__ unsigned pack32(float f) {
    unsigned u = __float_as_uint(f);
    return u ^ (unsigned)(((int)u >> 31) | 0x80000000);    // monotone map (3 VALU)
}

__device__ __forceinline__ void gload16(const void* g, void* l) {
    __builtin_amdgcn_global_load_lds(
        (const __attribute__((address_space(1))) unsigned*)g,
        (__attribute__((address_space(3))) unsigned*)l, 16, 0, 0);
}

// ---------------- Kernel 1: fused fp32 -> bf16 + row sq-norms ----------------
// blocks [0,Q): X rows (no sq); blocks [Q, Q+NTRAIN): Xt rows (with sq)
__global__ void prep_kernel(const float* __restrict__ X,
                            const float* __restrict__ Xt,
                            unsigned short* __restrict__ Xb,
                            unsigned short* __restrict__ Tb,
                            float* __restrict__ tsq) {
    __shared__ float red[3];
    const int b = blockIdx.x;
    const int t = threadIdx.x;
    const bool isX = (b < Q);
    const int row = isX ? b : b - Q;
    const float* src = isX ? X : Xt;
    unsigned short* dst = isX ? Xb : Tb;
    float4 v = reinterpret_cast<const float4*>(src)[(size_t)row * (D / 4) + t];
    ushort4 o;
    o.x = f2b(v.x); o.y = f2b(v.y); o.z = f2b(v.z); o.w = f2b(v.w);
    reinterpret_cast<ushort4*>(dst)[(size_t)row * (D / 4) + t] = o;
    if (!isX) {   // block-uniform branch
        float s = v.x * v.x + v.y * v.y + v.z * v.z + v.w * v.w;
#pragma unroll
        for (int off = 32; off; off >>= 1) s += __shfl_down(s, off);
        if ((t & 63) == 0) red[t >> 6] = s;
        __syncthreads();
        if (t == 0) tsq[row] = red[0] + red[1] + red[2];
    }
}

// ---------------- Kernel 2: bf16 MFMA GEMM + per-tile top-8 ----------------
__global__ void __launch_bounds__(256, 3) knn_gemm_kernel(
    const unsigned short* __restrict__ Xb, const unsigned short* __restrict__ Tb,
    const float* __restrict__ tsq, unsigned* __restrict__ cand) {
    // smem union: [0,16384) A-tile bf16[128][64], [16384,32768) B-tile
    // epilogue: [0,32768) keys u16[128][128] (col-swizzled)
    __shared__ __align__(16) char smem[32768];
    const int tid  = threadIdx.x;
    const int wave = tid >> 6, lane = tid & 63;
    const int rowTile = blockIdx.x, colTile = blockIdx.y;
    const int wr = wave >> 1, wc = wave & 1;

    const f32x4 zero = {0.f, 0.f, 0.f, 0.f};
    f32x4 acc[4][4];
#pragma unroll
    for (int m = 0; m < 4; m++)
#pragma unroll
        for (int n = 0; n < 4; n++) acc[m][n] = zero;

    // ---- prefetch epilogue tsq values (consumed after the K-loop) ----
    float tsqv[4];
#pragma unroll
    for (int n = 0; n < 4; n++)
        tsqv[n] = tsq[colTile * BN + wc * 64 + n * 16 + (lane & 15)];

    // ---- hoisted swizzled LDS frag byte-offsets (kt-invariant) ----
    int aOff[4][2], bOff[4][2];
#pragma unroll
    for (int m = 0; m < 4; m++) {
        const int rowA = wr * 64 + m * 16 + (lane & 15);
        const int rowB = wc * 64 + m * 16 + (lane & 15);
#pragma unroll
        for (int kk = 0; kk < 2; kk++) {
            const int g = kk * 4 + (lane >> 4);
            aOff[m][kk] = rowA * 128 + ((g ^ (rowA & 7)) * 16);
            bOff[m][kk] = rowB * 128 + ((g ^ (rowB & 7)) * 16);
        }
    }

    // ---- hoisted staging pointers: lds byte = c*4096 + wave*1024 + lane*16 ----
    const int s_row = wave * 8 + (lane >> 3);
    const int s_col = (((lane & 7) ^ (s_row & 7)) * 8);
    const unsigned short* pA[4];
    const unsigned short* pB[4];
#pragma unroll
    for (int c = 0; c < 4; c++) {
        pA[c] = Xb + (size_t)(rowTile * BM + c * 32 + s_row) * D + s_col;
        pB[c] = Tb + (size_t)(colTile * BN + c * 32 + s_row) * D + s_col;
    }
    char* Asm = smem;
    char* Bsm = smem + 16384;

#pragma unroll
    for (int kt = 0; kt < KT; ++kt) {
        const int k0 = kt * BK;
        __syncthreads();
#pragma unroll
        for (int c = 0; c < 4; ++c) {
            gload16(pA[c] + k0, Asm + c * 4096 + wave * 1024);
            gload16(pB[c] + k0, Bsm + c * 4096 + wave * 1024);
        }
        __syncthreads();
#pragma unroll
        for (int kk = 0; kk < 2; ++kk) {
            short8 a[4], b[4];
#pragma unroll
            for (int m = 0; m < 4; m++) a[m] = *(const short8*)(Asm + aOff[m][kk]);
#pragma unroll
            for (int n = 0; n < 4; n++) b[n] = *(const short8*)(Bsm + bOff[n][kk]);
#pragma unroll
            for (int m = 0; m < 4; m++)
#pragma unroll
                for (int n = 0; n < 4; n++)
                    acc[m][n] = __builtin_amdgcn_mfma_f32_16x16x32_bf16(a[m], b[n], acc[m][n], 0, 0, 0);
        }
    }
    __syncthreads();   // all MFMA-feeding ds_reads done before key overwrite

    // keys: key = tsq[col] - 2*cross; store u16 at col ^ ((row&12)<<2)
    unsigned short* keys = (unsigned short*)smem;   // [128][128] swizzled
    const int crow = wr * 64 + ((lane >> 4) << 2);
    const int ccol = wc * 64 + (lane & 15);
#pragma unroll
    for (int m = 0; m < 4; m++)
#pragma unroll
        for (int n = 0; n < 4; n++)
#pragma unroll
            for (int r = 0; r < 4; r++) {
                const int row = crow + m * 16 + r;
                const int col = ccol + n * 16;
                float key = fmaf(-2.f, acc[m][n][r], tsqv[n]);
                keys[row * 128 + (col ^ ((row & 12) << 2))] =
                    (unsigned short)(pack32(key) >> 16);
            }
    __syncthreads();

    // branchless per-half top-4: 2 threads/row, each scans 32 u32 words (64 cols)
    const int srow = tid >> 1, h = tid & 1;
    const unsigned sx = (unsigned)((srow & 12) << 2);
    const unsigned* keys32 = (const unsigned*)smem;
    const unsigned base = (unsigned)(srow * 64 + h * 32);
    const unsigned gcb = (unsigned)(colTile * BN + h * 64);
    unsigned m1 = ~0u, m2 = ~0u, m3 = ~0u, m4 = ~0u;
#pragma unroll 8
    for (int ii = 0; ii < 32; ++ii) {
        const unsigned w = (unsigned)((ii + srow) & 31);
        const unsigned pair = keys32[base + w];
        const unsigned gc = gcb + ((w * 2) ^ sx);
        const unsigned v0 = (pair << 16) | gc;
        const unsigned v1 = (pair & 0xFFFF0000u) | (gc + 1);
        unsigned t0, t1, t2;
        t0 = max(m1, v0); m1 = min(m1, v0);
        t1 = max(m2, t0); m2 = min(m2, t0);
        t2 = max(m3, t1); m3 = min(m3, t1);
        m4 = min(m4, t2);
        t0 = max(m1, v1); m1 = min(m1, v1);
        t1 = max(m2, t0); m2 = min(m2, t0);
        t2 = max(m3, t1); m3 = min(m3, t1);
        m4 = min(m4, t2);
    }
    uint4 outv = {m1, m2, m3, m4};
    *reinterpret_cast<uint4*>(
        cand + ((size_t)(rowTile * BM + srow) * NCT + colTile) * TSEL + h * 4) = outv;
}

// ---------------- Kernel 3: approx top-16 -> exact fp32 re-rank -> mean ----------------
__global__ void __launch_bounds__(256) knn_reduce_kernel(
    const float* __restrict__ X, const float* __restrict__ Xt,
    const float* __restrict__ tsq, const float* __restrict__ y,
    const unsigned* __restrict__ cand, float* __restrict__ out) {
    __shared__ unsigned cl[4096];
    __shared__ float xrow[D];
    __shared__ float red[4];
    __shared__ unsigned wmin[4];
    __shared__ float xsqs;
    __shared__ unsigned sel[16];
    __shared__ float exd[16];
    __shared__ unsigned exi[16];
    const int q = blockIdx.x;
    const int tid = threadIdx.x;
    const int lane = tid & 63, wave = tid >> 6;

    const unsigned* cq = cand + (size_t)q * (NCT * TSEL);
#pragma unroll
    for (int j = 0; j < 16; j++) cl[j * 256 + tid] = cq[j * 256 + tid];
    if (tid < D / 4)
        ((float4*)xrow)[tid] = ((const float4*)(X + (size_t)q * D))[tid];
    __syncthreads();

    float xs = 0.f;
#pragma unroll
    for (int j = 0; j < 3; j++) { float v = xrow[tid + j * 256]; xs = fmaf(v, v, xs); }
#pragma unroll
    for (int off = 32; off; off >>= 1) xs += __shfl_down(xs, off);
    if (lane == 0) red[wave] = xs;
    __syncthreads();
    if (tid == 0) xsqs = red[0] + red[1] + red[2] + red[3];

    for (int r = 0; r < 16; r++) {
        unsigned mn = 0xFFFFFFFFu;
#pragma unroll
        for (int j = 0; j < 16; j++) { unsigned v = cl[tid + 256 * j]; mn = v < mn ? v : mn; }
#pragma unroll
        for (int off = 32; off; off >>= 1) {
            unsigned o = (unsigned)__shfl_xor((int)mn, off);
            mn = o < mn ? o : mn;
        }
        if (lane == 0) wmin[wave] = mn;
        __syncthreads();
        unsigned m01 = wmin[0] < wmin[1] ? wmin[0] : wmin[1];
        unsigned m23 = wmin[2] < wmin[3] ? wmin[2] : wmin[3];
        unsigned m = m01 < m23 ? m01 : m23;
        if (tid == 0) sel[r] = m;
#pragma unroll
        for (int j = 0; j < 16; j++)
            if (cl[tid + 256 * j] == m) cl[tid + 256 * j] = 0xFFFFFFFFu;
        __syncthreads();
    }

    for (int cc = wave; cc < 16; cc += 4) {
        const unsigned id = sel[cc] & 0xFFFFu;
        const float* trow = Xt + (size_t)id * D;
        float s = 0.f;
#pragma unroll
        for (int j = 0; j < 12; j++) s = fmaf(xrow[lane + j * 64], trow[lane + j * 64], s);
#pragma unroll
        for (int off = 32; off; off >>= 1) s += __shfl_xor(s, off);
        if (lane == 0) {
            float d2 = xsqs + tsq[id] - 2.f * s;
            exd[cc] = sqrtf(fmaxf(d2, 0.f));
            exi[cc] = id;
        }
    }
    __syncthreads();

    if (tid == 0) {
        bool taken[16];
#pragma unroll
        for (int j = 0; j < 16; j++) taken[j] = false;
        float accy = 0.f;
        for (int k = 0; k < KNN; k++) {
            int best = -1;
            for (int j = 0; j < 16; j++) {
                if (taken[j]) continue;
                if (best < 0 || exd[j] < exd[best] ||
                    (exd[j] == exd[best] && exi[j] < exi[best])) best = j;
            }
            taken[best] = true;
            accy += y[exi[best]];
        }
        out[q] = accy / 7.0f;
    }
}

extern "C" void kernel_launch(void* const* d_in, const int* in_sizes, int n_in,
                              void* d_out, int out_size, void* d_ws, size_t ws_size,
                              hipStream_t stream) {
    const float* X  = (const float*)d_in[0];
    const float* Xt = (const float*)d_in[1];
    const float* y  = (const float*)d_in[2];
    float* out = (float*)d_out;
    char* ws = (char*)d_ws;
    unsigned short* Xb = (unsigned short*)(ws + XB_OFF);
    unsigned short* Tb = (unsigned short*)(ws + TB_OFF);
    float* tsq = (float*)(ws + TSQ_OFF);
    unsigned* cand = (unsigned*)(ws + CAND_OFF);

    prep_kernel<<<dim3(Q + NTRAIN), dim3(192), 0, stream>>>(X, Xt, Xb, Tb, tsq);
    knn_gemm_kernel<<<dim3(Q / BM, NCT), dim3(256), 0, stream>>>(Xb, Tb, tsq, cand);
    knn_reduce_kernel<<<dim3(Q), dim3(256), 0, stream>>>(X, Xt, tsq, y, cand, out);
}